// Round 1
// 110.010 us; speedup vs baseline: 1.0659x; 1.0659x over previous
//
#include <hip/hip_runtime.h>

#define B_  8
#define TE_ 256
#define TD_ 128
#define HE_ 512

typedef __attribute__((ext_vector_type(8))) short short8v;
typedef __attribute__((ext_vector_type(4))) float f32x4;

#define C2 2.8853900817779268f   // 2*log2(e)

// wave64 sum via DPP (VALU, no LDS): result valid in lane 63 only.
__device__ __forceinline__ float wave_red_add(float s) {
#define DPPADD(CTRL) \
  s += __int_as_float(__builtin_amdgcn_update_dpp(0, __float_as_int(s), CTRL, 0xf, 0xf, true))
  DPPADD(0x111);  // row_shr:1
  DPPADD(0x112);  // row_shr:2
  DPPADD(0x114);  // row_shr:4
  DPPADD(0x118);  // row_shr:8  -> lane15 of each row holds row sum
  DPPADD(0x142);  // row_bcast:15
  DPPADD(0x143);  // row_bcast:31 -> lane 63 = total
#undef DPPADD
  return s;
}

// ---- gemm_fused: Cws[3072,512] = [enc;dec] @ (Wa|Ua), trunc-split 3-term bf16 ----
// R11/R13 config. NEW (R14): epilogue stores exp2(C2*x) for ALL rows:
//   enc rows (0..2047)  -> EW = e^{2*Ws}
//   dec rows (2048..3071)-> EU = e^{2*Uh}   (hoists 16 waves x 16 exp2/thread out of attn)
__global__ __launch_bounds__(512) void gemm_fused(
    const float* __restrict__ enc, const float* __restrict__ dec,
    const float* __restrict__ Wa, const float* __restrict__ Ua,
    float* __restrict__ C) {
  __shared__ short BT[2][32][512];    // 64 KB
  const int bid = blockIdx.x;
  const int mt = bid % 24, nt = bid / 24;
  const int m0 = mt * 128, n0 = nt * 32;
  const bool isenc = (mt < 16);
  const float* Bsrc = isenc ? Wa : Ua;
  const float* Asrc = isenc ? enc + (size_t)m0 * 512
                            : dec + (size_t)(m0 - 2048) * 512;
  const int tid = threadIdx.x;
  {
    const int kp = tid >> 3;          // 0..63
    const int c4 = (tid & 7) * 4;
    for (int p = 0; p < 4; ++p) {
      const int k = 2 * kp + p * 128;              // even
      float4 v0 = *(const float4*)(Bsrc + (size_t)k * 512 + n0 + c4);
      float4 v1 = *(const float4*)(Bsrc + (size_t)(k + 1) * 512 + n0 + c4);
      const float a0[4] = {v0.x, v0.y, v0.z, v0.w};
      const float a1[4] = {v1.x, v1.y, v1.z, v1.w};
      const int kc = k >> 3, klo = k & 7;
#pragma unroll
      for (int q = 0; q < 4; ++q) {
        const int n = c4 + q;
        unsigned u0 = __float_as_uint(a0[q]);
        unsigned u1 = __float_as_uint(a1[q]);
        unsigned hi32 = __builtin_amdgcn_perm(u1, u0, 0x07060302);
        float l0 = a0[q] - __uint_as_float(u0 & 0xffff0000u);
        float l1 = a1[q] - __uint_as_float(u1 & 0xffff0000u);
        unsigned lo32 = __builtin_amdgcn_perm(__float_as_uint(l1), __float_as_uint(l0), 0x07060302);
        const int slot = (kc & ~7) | ((kc ^ n) & 7);
        *(unsigned*)&BT[0][n][slot * 8 + klo] = hi32;
        *(unsigned*)&BT[1][n][slot * 8 + klo] = lo32;
      }
    }
  }
  __syncthreads();
  const int w = tid >> 6, lane = tid & 63;
  const int fm = lane & 15, fc = lane >> 4;
  const float* Ap = Asrc + (size_t)(w * 16 + fm) * 512 + fc * 8;
  f32x4 acc0 = {}, acc1 = {};
  float4 pfa[2], pfb[2];
  pfa[0] = *(const float4*)(Ap);
  pfb[0] = *(const float4*)(Ap + 4);
  pfa[1] = *(const float4*)(Ap + 32);
  pfb[1] = *(const float4*)(Ap + 36);
  for (int it = 0; it < 16; ++it) {
    const float4 fa = pfa[it & 1];
    const float4 fb = pfb[it & 1];
    if (it < 14) {
      pfa[it & 1] = *(const float4*)(Ap + (it + 2) * 32);
      pfb[it & 1] = *(const float4*)(Ap + (it + 2) * 32 + 4);
    }
    const float af[8] = {fa.x, fa.y, fa.z, fa.w, fb.x, fb.y, fb.z, fb.w};
    union { unsigned u[4]; short8v s; } ahu, alu;
#pragma unroll
    for (int e = 0; e < 4; ++e) {
      unsigned u0 = __float_as_uint(af[2 * e]);
      unsigned u1 = __float_as_uint(af[2 * e + 1]);
      ahu.u[e] = __builtin_amdgcn_perm(u1, u0, 0x07060302);
      float l0 = af[2 * e]     - __uint_as_float(u0 & 0xffff0000u);
      float l1 = af[2 * e + 1] - __uint_as_float(u1 & 0xffff0000u);
      alu.u[e] = __builtin_amdgcn_perm(__float_as_uint(l1), __float_as_uint(l0), 0x07060302);
    }
    const short8v ah = ahu.s, al = alu.s;
    const int kc = it * 4 + fc;
    const int base = kc & ~7;
    const int s0 = (base | ((kc ^ fm) & 7)) * 8;
    const int s1 = (base | ((kc ^ (16 + fm)) & 7)) * 8;
    short8v bh0 = *(const short8v*)&BT[0][fm][s0];
    short8v bl0 = *(const short8v*)&BT[1][fm][s0];
    short8v bh1 = *(const short8v*)&BT[0][16 + fm][s1];
    short8v bl1 = *(const short8v*)&BT[1][16 + fm][s1];
    acc0 = __builtin_amdgcn_mfma_f32_16x16x32_bf16(ah, bh0, acc0, 0, 0, 0);
    acc1 = __builtin_amdgcn_mfma_f32_16x16x32_bf16(ah, bh1, acc1, 0, 0, 0);
    acc0 = __builtin_amdgcn_mfma_f32_16x16x32_bf16(ah, bl0, acc0, 0, 0, 0);
    acc1 = __builtin_amdgcn_mfma_f32_16x16x32_bf16(ah, bl1, acc1, 0, 0, 0);
    acc0 = __builtin_amdgcn_mfma_f32_16x16x32_bf16(al, bh0, acc0, 0, 0, 0);
    acc1 = __builtin_amdgcn_mfma_f32_16x16x32_bf16(al, bh1, acc1, 0, 0, 0);
  }
  const int row = m0 + w * 16 + fc * 4;
  float* Cp = C + (size_t)row * 512 + n0 + fm;
#pragma unroll
  for (int r = 0; r < 4; ++r)
    Cp[(size_t)r * 512] = __builtin_amdgcn_exp2f(C2 * acc0[r]);
#pragma unroll
  for (int r = 0; r < 4; ++r)
    Cp[(size_t)r * 512 + 16] = __builtin_amdgcn_exp2f(C2 * acc1[r]);
}

// ---- attn_fused: logits + softmax only (context moved to ctx_gemm) ----
// EWs holds e^{2Ws}; EU holds e^{2Uh}. tanh term = v - 2v*rcp(EW*EU + 1).
__global__ __launch_bounds__(1024) void attn_fused(
    const float* __restrict__ EWs, const float* __restrict__ EU,
    const float* __restrict__ Va, float* __restrict__ e_out) {
  __shared__ float sEU[2][HE_];
  __shared__ float sV[HE_];
  __shared__ float sE[2][TE_];
  __shared__ float sRed[8];
  __shared__ float sNorm[2];
  const int tid = threadIdx.x;
  const int b  = blockIdx.x & 7;          // XCD-aligned b partition
  const int d0 = (blockIdx.x >> 3) * 2;   // 64 d-tiles x 8 b = 512 blocks
  if (tid < 256)
    ((float4*)sEU)[tid] = ((const float4*)(EU + (size_t)(b * TD_ + d0) * HE_))[tid];
  else if (tid < 384)
    ((float4*)sV)[tid - 256] = ((const float4*)Va)[tid - 256];
  __syncthreads();
  const int lane = tid & 63, w = tid >> 6;   // 16 waves
  const int tb = w * 16;                     // 16 t per wave, both d's
  const int h0 = lane * 8;
  float eU[2][8], vv2[8], sumv = 0.f;
#pragma unroll
  for (int j = 0; j < 8; ++j) {
    const float vj = sV[h0 + j];
    sumv += vj;
    vv2[j] = 2.0f * vj;
    eU[0][j] = sEU[0][h0 + j];   // pre-exp'd in gemm epilogue
    eU[1][j] = sEU[1][h0 + j];
  }
  const float* pw = EWs + ((size_t)b * TE_ + tb) * HE_ + h0;
  float4 a0 = *(const float4*)(pw);
  float4 a1 = *(const float4*)(pw + 4);
  float s0, s1;
#define TELT2(X, J) { \
    float E0 = (X) * eU[0][J]; \
    float E1 = (X) * eU[1][J]; \
    float r0 = __builtin_amdgcn_rcpf(E0 + 1.0f); \
    float r1 = __builtin_amdgcn_rcpf(E1 + 1.0f); \
    s0 = fmaf(-vv2[J], r0, s0); s1 = fmaf(-vv2[J], r1, s1); }
  for (int ti = 0; ti < 16; ++ti) {
    const float* pn = pw + HE_;
    float4 n0 = *(const float4*)(pn);       // depth-1 prefetch (R13 best)
    float4 n1 = *(const float4*)(pn + 4);
    s0 = s1 = sumv;
    TELT2(a0.x, 0) TELT2(a0.y, 1) TELT2(a0.z, 2) TELT2(a0.w, 3)
    TELT2(a1.x, 4) TELT2(a1.y, 5) TELT2(a1.z, 6) TELT2(a1.w, 7)
    s0 = wave_red_add(s0);
    s1 = wave_red_add(s1);
    if (lane == 63) {
      sE[0][tb + ti] = s0;
      sE[1][tb + ti] = s1;
    }
    a0 = n0; a1 = n1;
    pw = pn;
  }
  __syncthreads();
  // softmax (no max-subtraction: |logit| <= sum|V| ~ 21, exp safe in fp32)
  if (tid < 512) {
    const int dA = tid >> 8, t = tid & 255;
    const float ex = __expf(sE[dA][t]);
    float sum = wave_red_add(ex);
    if (lane == 63) sRed[w] = sum;           // waves 0..3 -> d0, 4..7 -> d1
    __syncthreads();
    if (tid < 2)
      sNorm[tid] = 1.0f / (sRed[tid * 4] + sRed[tid * 4 + 1] + sRed[tid * 4 + 2] + sRed[tid * 4 + 3]);
    __syncthreads();
    e_out[(size_t)(b * TD_ + d0 + dA) * TE_ + t] = ex * sNorm[dA];
  } else {
    __syncthreads();
    __syncthreads();
  }
}

// ---- ctx_gemm: c[b] = e[b] @ enc[b]  ([128,256]x[256,512] per b), 3-term bf16 ----
// Replaces attn phase 3 (was 512 MB of scalar L2 streaming). 128 blocks x 512 thr,
// b = bid&7 keeps each b's enc/e slice on the XCD whose L2 attn just warmed.
__global__ __launch_bounds__(512) void ctx_gemm(
    const float* __restrict__ e, const float* __restrict__ enc,
    float* __restrict__ c_out) {
  __shared__ short BT[2][32][256];   // 32 KB
  const int bid = blockIdx.x;
  const int b = bid & 7, nt = bid >> 3;    // 16 n-tiles of 32
  const int n0 = nt * 32;
  const float* A    = e   + (size_t)b * TD_ * TE_;   // [128,256]
  const float* Bsrc = enc + (size_t)b * TE_ * HE_;   // [256,512]
  const int tid = threadIdx.x;
  {
    const int kp = tid >> 3;          // 0..63
    const int c4 = (tid & 7) * 4;
    for (int p = 0; p < 2; ++p) {
      const int k = 2 * kp + p * 128;              // even, covers 0..254
      float4 v0 = *(const float4*)(Bsrc + (size_t)k * HE_ + n0 + c4);
      float4 v1 = *(const float4*)(Bsrc + (size_t)(k + 1) * HE_ + n0 + c4);
      const float a0[4] = {v0.x, v0.y, v0.z, v0.w};
      const float a1[4] = {v1.x, v1.y, v1.z, v1.w};
      const int kc = k >> 3, klo = k & 7;
#pragma unroll
      for (int q = 0; q < 4; ++q) {
        const int n = c4 + q;
        unsigned u0 = __float_as_uint(a0[q]);
        unsigned u1 = __float_as_uint(a1[q]);
        unsigned hi32 = __builtin_amdgcn_perm(u1, u0, 0x07060302);
        float l0 = a0[q] - __uint_as_float(u0 & 0xffff0000u);
        float l1 = a1[q] - __uint_as_float(u1 & 0xffff0000u);
        unsigned lo32 = __builtin_amdgcn_perm(__float_as_uint(l1), __float_as_uint(l0), 0x07060302);
        const int slot = (kc & ~7) | ((kc ^ n) & 7);
        *(unsigned*)&BT[0][n][slot * 8 + klo] = hi32;
        *(unsigned*)&BT[1][n][slot * 8 + klo] = lo32;
      }
    }
  }
  __syncthreads();
  const int w = tid >> 6, lane = tid & 63;
  const int fm = lane & 15, fc = lane >> 4;
  const float* Ap = A + (size_t)(w * 16 + fm) * TE_ + fc * 8;
  f32x4 acc0 = {}, acc1 = {};
  for (int it = 0; it < 8; ++it) {
    const float4 fa = *(const float4*)(Ap + it * 32);
    const float4 fb = *(const float4*)(Ap + it * 32 + 4);
    const float af[8] = {fa.x, fa.y, fa.z, fa.w, fb.x, fb.y, fb.z, fb.w};
    union { unsigned u[4]; short8v s; } ahu, alu;
#pragma unroll
    for (int q = 0; q < 4; ++q) {
      unsigned u0 = __float_as_uint(af[2 * q]);
      unsigned u1 = __float_as_uint(af[2 * q + 1]);
      ahu.u[q] = __builtin_amdgcn_perm(u1, u0, 0x07060302);
      float l0 = af[2 * q]     - __uint_as_float(u0 & 0xffff0000u);
      float l1 = af[2 * q + 1] - __uint_as_float(u1 & 0xffff0000u);
      alu.u[q] = __builtin_amdgcn_perm(__float_as_uint(l1), __float_as_uint(l0), 0x07060302);
    }
    const short8v ah = ahu.s, al = alu.s;
    const int kc = it * 4 + fc;
    const int base = kc & ~7;
    const int s0 = (base | ((kc ^ fm) & 7)) * 8;
    const int s1 = (base | ((kc ^ (16 + fm)) & 7)) * 8;
    short8v bh0 = *(const short8v*)&BT[0][fm][s0];
    short8v bl0 = *(const short8v*)&BT[1][fm][s0];
    short8v bh1 = *(const short8v*)&BT[0][16 + fm][s1];
    short8v bl1 = *(const short8v*)&BT[1][16 + fm][s1];
    acc0 = __builtin_amdgcn_mfma_f32_16x16x32_bf16(ah, bh0, acc0, 0, 0, 0);
    acc1 = __builtin_amdgcn_mfma_f32_16x16x32_bf16(ah, bh1, acc1, 0, 0, 0);
    acc0 = __builtin_amdgcn_mfma_f32_16x16x32_bf16(ah, bl0, acc0, 0, 0, 0);
    acc1 = __builtin_amdgcn_mfma_f32_16x16x32_bf16(ah, bl1, acc1, 0, 0, 0);
    acc0 = __builtin_amdgcn_mfma_f32_16x16x32_bf16(al, bh0, acc0, 0, 0, 0);
    acc1 = __builtin_amdgcn_mfma_f32_16x16x32_bf16(al, bh1, acc1, 0, 0, 0);
  }
  const int row = w * 16 + fc * 4;
  float* Cp = c_out + (size_t)(b * TD_ + row) * HE_ + n0 + fm;
#pragma unroll
  for (int r = 0; r < 4; ++r) Cp[(size_t)r * HE_] = acc0[r];
#pragma unroll
  for (int r = 0; r < 4; ++r) Cp[(size_t)r * HE_ + 16] = acc1[r];
}

extern "C" void kernel_launch(void* const* d_in, const int* in_sizes, int n_in,
                              void* d_out, int out_size, void* d_ws, size_t ws_size,
                              hipStream_t stream) {
  const float* enc = (const float*)d_in[0];   // [8,256,512]
  const float* dec = (const float*)d_in[1];   // [8,128,512]
  const float* Wa  = (const float*)d_in[2];   // [512,512]
  const float* Ua  = (const float*)d_in[3];   // [512,512]
  const float* Va  = (const float*)d_in[4];   // [512,1]
  float* c_out = (float*)d_out;
  float* e_out = c_out + (size_t)B_ * TD_ * HE_;
  float* Cws = (float*)d_ws;                   // [3072,512] fp32 = 6 MB
  const float* EWs = Cws;                      // rows 0..2047: e^{2Ws}
  const float* EU  = Cws + (size_t)2048 * 512; // rows 2048..3071: e^{2Uh}
  gemm_fused<<<384, 512, 0, stream>>>(enc, dec, Wa, Ua, Cws);
  attn_fused<<<512, 1024, 0, stream>>>(EWs, EU, Va, e_out);
  ctx_gemm<<<128, 512, 0, stream>>>(e_out, enc, c_out);
}

// Round 2
// 109.669 us; speedup vs baseline: 1.0692x; 1.0031x over previous
//
#include <hip/hip_runtime.h>

#define B_  8
#define TE_ 256
#define TD_ 128
#define HE_ 512

typedef __attribute__((ext_vector_type(8))) short short8v;
typedef __attribute__((ext_vector_type(4))) float f32x4;
typedef __attribute__((ext_vector_type(2))) float f32x2;

#define C2 2.8853900817779268f   // 2*log2(e)

// wave64 sum via DPP (VALU, no LDS): result valid in lane 63 only.
__device__ __forceinline__ float wave_red_add(float s) {
#define DPPADD(CTRL) \
  s += __int_as_float(__builtin_amdgcn_update_dpp(0, __float_as_int(s), CTRL, 0xf, 0xf, true))
  DPPADD(0x111);  // row_shr:1
  DPPADD(0x112);  // row_shr:2
  DPPADD(0x114);  // row_shr:4
  DPPADD(0x118);  // row_shr:8  -> lane15 of each row holds row sum
  DPPADD(0x142);  // row_bcast:15
  DPPADD(0x143);  // row_bcast:31 -> lane 63 = total
#undef DPPADD
  return s;
}

// 16-lane row sum only (4 DPP steps): lanes 15/31/47/63 hold their row's sum.
__device__ __forceinline__ float row_red_add(float s) {
#define DPPADD(CTRL) \
  s += __int_as_float(__builtin_amdgcn_update_dpp(0, __float_as_int(s), CTRL, 0xf, 0xf, true))
  DPPADD(0x111);
  DPPADD(0x112);
  DPPADD(0x114);
  DPPADD(0x118);
#undef DPPADD
  return s;
}

// packed 2xf32 fma: d = a*b + c per 32-bit half (VOP3P, full rate)
__device__ __forceinline__ f32x2 pk_fma(f32x2 a, f32x2 b, f32x2 c) {
  f32x2 d;
  asm("v_pk_fma_f32 %0, %1, %2, %3" : "=v"(d) : "v"(a), "v"(b), "v"(c));
  return d;
}

// ---- gemm_fused: Cws[3072,512] = [enc;dec] @ (Wa|Ua), trunc-split 3-term bf16 ----
// Epilogue stores exp2(C2*x) for ALL rows:
//   enc rows (0..2047)   -> EW = e^{2*Ws}
//   dec rows (2048..3071)-> EU = e^{2*Uh}
__global__ __launch_bounds__(512) void gemm_fused(
    const float* __restrict__ enc, const float* __restrict__ dec,
    const float* __restrict__ Wa, const float* __restrict__ Ua,
    float* __restrict__ C) {
  __shared__ short BT[2][32][512];    // 64 KB
  const int bid = blockIdx.x;
  const int mt = bid % 24, nt = bid / 24;
  const int m0 = mt * 128, n0 = nt * 32;
  const bool isenc = (mt < 16);
  const float* Bsrc = isenc ? Wa : Ua;
  const float* Asrc = isenc ? enc + (size_t)m0 * 512
                            : dec + (size_t)(m0 - 2048) * 512;
  const int tid = threadIdx.x;
  {
    const int kp = tid >> 3;          // 0..63
    const int c4 = (tid & 7) * 4;
    for (int p = 0; p < 4; ++p) {
      const int k = 2 * kp + p * 128;              // even
      float4 v0 = *(const float4*)(Bsrc + (size_t)k * 512 + n0 + c4);
      float4 v1 = *(const float4*)(Bsrc + (size_t)(k + 1) * 512 + n0 + c4);
      const float a0[4] = {v0.x, v0.y, v0.z, v0.w};
      const float a1[4] = {v1.x, v1.y, v1.z, v1.w};
      const int kc = k >> 3, klo = k & 7;
#pragma unroll
      for (int q = 0; q < 4; ++q) {
        const int n = c4 + q;
        unsigned u0 = __float_as_uint(a0[q]);
        unsigned u1 = __float_as_uint(a1[q]);
        unsigned hi32 = __builtin_amdgcn_perm(u1, u0, 0x07060302);
        float l0 = a0[q] - __uint_as_float(u0 & 0xffff0000u);
        float l1 = a1[q] - __uint_as_float(u1 & 0xffff0000u);
        unsigned lo32 = __builtin_amdgcn_perm(__float_as_uint(l1), __float_as_uint(l0), 0x07060302);
        const int slot = (kc & ~7) | ((kc ^ n) & 7);
        *(unsigned*)&BT[0][n][slot * 8 + klo] = hi32;
        *(unsigned*)&BT[1][n][slot * 8 + klo] = lo32;
      }
    }
  }
  __syncthreads();
  const int w = tid >> 6, lane = tid & 63;
  const int fm = lane & 15, fc = lane >> 4;
  const float* Ap = Asrc + (size_t)(w * 16 + fm) * 512 + fc * 8;
  f32x4 acc0 = {}, acc1 = {};
  float4 pfa[2], pfb[2];
  pfa[0] = *(const float4*)(Ap);
  pfb[0] = *(const float4*)(Ap + 4);
  pfa[1] = *(const float4*)(Ap + 32);
  pfb[1] = *(const float4*)(Ap + 36);
  for (int it = 0; it < 16; ++it) {
    const float4 fa = pfa[it & 1];
    const float4 fb = pfb[it & 1];
    if (it < 14) {
      pfa[it & 1] = *(const float4*)(Ap + (it + 2) * 32);
      pfb[it & 1] = *(const float4*)(Ap + (it + 2) * 32 + 4);
    }
    const float af[8] = {fa.x, fa.y, fa.z, fa.w, fb.x, fb.y, fb.z, fb.w};
    union { unsigned u[4]; short8v s; } ahu, alu;
#pragma unroll
    for (int e = 0; e < 4; ++e) {
      unsigned u0 = __float_as_uint(af[2 * e]);
      unsigned u1 = __float_as_uint(af[2 * e + 1]);
      ahu.u[e] = __builtin_amdgcn_perm(u1, u0, 0x07060302);
      float l0 = af[2 * e]     - __uint_as_float(u0 & 0xffff0000u);
      float l1 = af[2 * e + 1] - __uint_as_float(u1 & 0xffff0000u);
      alu.u[e] = __builtin_amdgcn_perm(__float_as_uint(l1), __float_as_uint(l0), 0x07060302);
    }
    const short8v ah = ahu.s, al = alu.s;
    const int kc = it * 4 + fc;
    const int base = kc & ~7;
    const int s0 = (base | ((kc ^ fm) & 7)) * 8;
    const int s1 = (base | ((kc ^ (16 + fm)) & 7)) * 8;
    short8v bh0 = *(const short8v*)&BT[0][fm][s0];
    short8v bl0 = *(const short8v*)&BT[1][fm][s0];
    short8v bh1 = *(const short8v*)&BT[0][16 + fm][s1];
    short8v bl1 = *(const short8v*)&BT[1][16 + fm][s1];
    acc0 = __builtin_amdgcn_mfma_f32_16x16x32_bf16(ah, bh0, acc0, 0, 0, 0);
    acc1 = __builtin_amdgcn_mfma_f32_16x16x32_bf16(ah, bh1, acc1, 0, 0, 0);
    acc0 = __builtin_amdgcn_mfma_f32_16x16x32_bf16(ah, bl0, acc0, 0, 0, 0);
    acc1 = __builtin_amdgcn_mfma_f32_16x16x32_bf16(ah, bl1, acc1, 0, 0, 0);
    acc0 = __builtin_amdgcn_mfma_f32_16x16x32_bf16(al, bh0, acc0, 0, 0, 0);
    acc1 = __builtin_amdgcn_mfma_f32_16x16x32_bf16(al, bh1, acc1, 0, 0, 0);
  }
  const int row = m0 + w * 16 + fc * 4;
  float* Cp = C + (size_t)row * 512 + n0 + fm;
#pragma unroll
  for (int r = 0; r < 4; ++r)
    Cp[(size_t)r * 512] = __builtin_amdgcn_exp2f(C2 * acc0[r]);
#pragma unroll
  for (int r = 0; r < 4; ++r)
    Cp[(size_t)r * 512 + 16] = __builtin_amdgcn_exp2f(C2 * acc1[r]);
}

// ---- attn_fused: logits + softmax. R15: 4 d's/block (256 blocks), v_pk_fma
// for E+1 (2 h-elems per instr), 4-step DPP reduce deferred to softmax phase.
// EWs holds e^{2Ws}; EU holds e^{2Uh}. tanh term = v - 2v*rcp(EW*EU + 1).
__global__ __launch_bounds__(1024) void attn_fused(
    const float* __restrict__ EWs, const float* __restrict__ EU,
    const float* __restrict__ Va, float* __restrict__ e_out) {
  __shared__ float sEU[4][HE_];      // 8 KB
  __shared__ float sV[HE_];          // 2 KB
  __shared__ float sE4[4][TE_][4];   // 16 KB: 4 row-partials per (d,t)
  __shared__ float sRed[16];
  __shared__ float sNorm[4];
  const int tid = threadIdx.x;
  const int b  = blockIdx.x & 7;          // XCD-aligned b partition
  const int d0 = (blockIdx.x >> 3) * 4;   // 32 d-tiles x 8 b = 256 blocks
  if (tid < 512)
    ((float4*)sEU)[tid] = ((const float4*)(EU + (size_t)(b * TD_ + d0) * HE_))[tid];
  else if (tid < 640)
    ((float4*)sV)[tid - 512] = ((const float4*)Va)[tid - 512];
  __syncthreads();
  const int lane = tid & 63, w = tid >> 6;   // 16 waves
  const int tb = w * 16;                     // 16 t per wave, 4 d's each
  const int h0 = lane * 8;
  f32x2 peU[4][4];
  float vv2[8], sumv = 0.f;
#pragma unroll
  for (int j = 0; j < 8; ++j) {
    const float vj = sV[h0 + j];
    sumv += vj;
    vv2[j] = 2.0f * vj;
  }
#pragma unroll
  for (int d = 0; d < 4; ++d)
#pragma unroll
    for (int jj = 0; jj < 4; ++jj)
      peU[d][jj] = ((const f32x2*)&sEU[d][h0])[jj];
  const f32x2 one2 = {1.0f, 1.0f};
  const float* pw = EWs + ((size_t)b * TE_ + tb) * HE_ + h0;
  f32x2 pX[4];
#pragma unroll
  for (int jj = 0; jj < 4; ++jj) pX[jj] = ((const f32x2*)pw)[jj];
  for (int ti = 0; ti < 16; ++ti) {
    const float* pn = pw + HE_;
    f32x2 nX[4];                           // depth-1 prefetch
#pragma unroll
    for (int jj = 0; jj < 4; ++jj) nX[jj] = ((const f32x2*)pn)[jj];
    float s0 = sumv, s1 = sumv, s2 = sumv, s3 = sumv;
#pragma unroll
    for (int jj = 0; jj < 4; ++jj) {
      const float va = vv2[2 * jj], vb = vv2[2 * jj + 1];
      f32x2 e0 = pk_fma(pX[jj], peU[0][jj], one2);   // {X*eU+1} x2 h
      f32x2 e1 = pk_fma(pX[jj], peU[1][jj], one2);
      f32x2 e2 = pk_fma(pX[jj], peU[2][jj], one2);
      f32x2 e3 = pk_fma(pX[jj], peU[3][jj], one2);
      s0 = fmaf(-va, __builtin_amdgcn_rcpf(e0.x), s0);
      s0 = fmaf(-vb, __builtin_amdgcn_rcpf(e0.y), s0);
      s1 = fmaf(-va, __builtin_amdgcn_rcpf(e1.x), s1);
      s1 = fmaf(-vb, __builtin_amdgcn_rcpf(e1.y), s1);
      s2 = fmaf(-va, __builtin_amdgcn_rcpf(e2.x), s2);
      s2 = fmaf(-vb, __builtin_amdgcn_rcpf(e2.y), s2);
      s3 = fmaf(-va, __builtin_amdgcn_rcpf(e3.x), s3);
      s3 = fmaf(-vb, __builtin_amdgcn_rcpf(e3.y), s3);
    }
    s0 = row_red_add(s0);
    s1 = row_red_add(s1);
    s2 = row_red_add(s2);
    s3 = row_red_add(s3);
    if ((lane & 15) == 15) {
      const int r = lane >> 4;
      sE4[0][tb + ti][r] = s0;
      sE4[1][tb + ti][r] = s1;
      sE4[2][tb + ti][r] = s2;
      sE4[3][tb + ti][r] = s3;
    }
    pX[0] = nX[0]; pX[1] = nX[1]; pX[2] = nX[2]; pX[3] = nX[3];
    pw = pn;
  }
  __syncthreads();
  // softmax: 1024 threads = 4 d x 256 t, no divergent branch.
  // (no max-subtraction: |logit| <= sum|V| ~ 21, exp safe in fp32)
  const int dA = tid >> 8, t = tid & 255;
  const float* q = sE4[dA][t];
  const float ex = __expf(q[0] + q[1] + q[2] + q[3]);
  float sum = wave_red_add(ex);
  if (lane == 63) sRed[w] = sum;             // waves 4d..4d+3 belong to d
  __syncthreads();
  if (tid < 4)
    sNorm[tid] = 1.0f / (sRed[tid * 4] + sRed[tid * 4 + 1] + sRed[tid * 4 + 2] + sRed[tid * 4 + 3]);
  __syncthreads();
  e_out[(size_t)(b * TD_ + d0 + dA) * TE_ + t] = ex * sNorm[dA];
}

// ---- ctx_gemm: c[b] = e[b] @ enc[b]  ([128,256]x[256,512] per b), 3-term bf16 ----
// 128 blocks x 512 thr; b = bid&7 keeps each b's enc/e slice on its XCD's L2.
__global__ __launch_bounds__(512) void ctx_gemm(
    const float* __restrict__ e, const float* __restrict__ enc,
    float* __restrict__ c_out) {
  __shared__ short BT[2][32][256];   // 32 KB
  const int bid = blockIdx.x;
  const int b = bid & 7, nt = bid >> 3;    // 16 n-tiles of 32
  const int n0 = nt * 32;
  const float* A    = e   + (size_t)b * TD_ * TE_;   // [128,256]
  const float* Bsrc = enc + (size_t)b * TE_ * HE_;   // [256,512]
  const int tid = threadIdx.x;
  {
    const int kp = tid >> 3;          // 0..63
    const int c4 = (tid & 7) * 4;
    for (int p = 0; p < 2; ++p) {
      const int k = 2 * kp + p * 128;              // even, covers 0..254
      float4 v0 = *(const float4*)(Bsrc + (size_t)k * HE_ + n0 + c4);
      float4 v1 = *(const float4*)(Bsrc + (size_t)(k + 1) * HE_ + n0 + c4);
      const float a0[4] = {v0.x, v0.y, v0.z, v0.w};
      const float a1[4] = {v1.x, v1.y, v1.z, v1.w};
      const int kc = k >> 3, klo = k & 7;
#pragma unroll
      for (int q = 0; q < 4; ++q) {
        const int n = c4 + q;
        unsigned u0 = __float_as_uint(a0[q]);
        unsigned u1 = __float_as_uint(a1[q]);
        unsigned hi32 = __builtin_amdgcn_perm(u1, u0, 0x07060302);
        float l0 = a0[q] - __uint_as_float(u0 & 0xffff0000u);
        float l1 = a1[q] - __uint_as_float(u1 & 0xffff0000u);
        unsigned lo32 = __builtin_amdgcn_perm(__float_as_uint(l1), __float_as_uint(l0), 0x07060302);
        const int slot = (kc & ~7) | ((kc ^ n) & 7);
        *(unsigned*)&BT[0][n][slot * 8 + klo] = hi32;
        *(unsigned*)&BT[1][n][slot * 8 + klo] = lo32;
      }
    }
  }
  __syncthreads();
  const int w = tid >> 6, lane = tid & 63;
  const int fm = lane & 15, fc = lane >> 4;
  const float* Ap = A + (size_t)(w * 16 + fm) * TE_ + fc * 8;
  f32x4 acc0 = {}, acc1 = {};
  for (int it = 0; it < 8; ++it) {
    const float4 fa = *(const float4*)(Ap + it * 32);
    const float4 fb = *(const float4*)(Ap + it * 32 + 4);
    const float af[8] = {fa.x, fa.y, fa.z, fa.w, fb.x, fb.y, fb.z, fb.w};
    union { unsigned u[4]; short8v s; } ahu, alu;
#pragma unroll
    for (int q = 0; q < 4; ++q) {
      unsigned u0 = __float_as_uint(af[2 * q]);
      unsigned u1 = __float_as_uint(af[2 * q + 1]);
      ahu.u[q] = __builtin_amdgcn_perm(u1, u0, 0x07060302);
      float l0 = af[2 * q]     - __uint_as_float(u0 & 0xffff0000u);
      float l1 = af[2 * q + 1] - __uint_as_float(u1 & 0xffff0000u);
      alu.u[q] = __builtin_amdgcn_perm(__float_as_uint(l1), __float_as_uint(l0), 0x07060302);
    }
    const short8v ah = ahu.s, al = alu.s;
    const int kc = it * 4 + fc;
    const int base = kc & ~7;
    const int s0 = (base | ((kc ^ fm) & 7)) * 8;
    const int s1 = (base | ((kc ^ (16 + fm)) & 7)) * 8;
    short8v bh0 = *(const short8v*)&BT[0][fm][s0];
    short8v bl0 = *(const short8v*)&BT[1][fm][s0];
    short8v bh1 = *(const short8v*)&BT[0][16 + fm][s1];
    short8v bl1 = *(const short8v*)&BT[1][16 + fm][s1];
    acc0 = __builtin_amdgcn_mfma_f32_16x16x32_bf16(ah, bh0, acc0, 0, 0, 0);
    acc1 = __builtin_amdgcn_mfma_f32_16x16x32_bf16(ah, bh1, acc1, 0, 0, 0);
    acc0 = __builtin_amdgcn_mfma_f32_16x16x32_bf16(ah, bl0, acc0, 0, 0, 0);
    acc1 = __builtin_amdgcn_mfma_f32_16x16x32_bf16(ah, bl1, acc1, 0, 0, 0);
    acc0 = __builtin_amdgcn_mfma_f32_16x16x32_bf16(al, bh0, acc0, 0, 0, 0);
    acc1 = __builtin_amdgcn_mfma_f32_16x16x32_bf16(al, bh1, acc1, 0, 0, 0);
  }
  const int row = w * 16 + fc * 4;
  float* Cp = c_out + (size_t)(b * TD_ + row) * HE_ + n0 + fm;
#pragma unroll
  for (int r = 0; r < 4; ++r) Cp[(size_t)r * HE_] = acc0[r];
#pragma unroll
  for (int r = 0; r < 4; ++r) Cp[(size_t)r * HE_ + 16] = acc1[r];
}

extern "C" void kernel_launch(void* const* d_in, const int* in_sizes, int n_in,
                              void* d_out, int out_size, void* d_ws, size_t ws_size,
                              hipStream_t stream) {
  const float* enc = (const float*)d_in[0];   // [8,256,512]
  const float* dec = (const float*)d_in[1];   // [8,128,512]
  const float* Wa  = (const float*)d_in[2];   // [512,512]
  const float* Ua  = (const float*)d_in[3];   // [512,512]
  const float* Va  = (const float*)d_in[4];   // [512,1]
  float* c_out = (float*)d_out;
  float* e_out = c_out + (size_t)B_ * TD_ * HE_;
  float* Cws = (float*)d_ws;                   // [3072,512] fp32 = 6 MB
  const float* EWs = Cws;                      // rows 0..2047: e^{2Ws}
  const float* EU  = Cws + (size_t)2048 * 512; // rows 2048..3071: e^{2Uh}
  gemm_fused<<<384, 512, 0, stream>>>(enc, dec, Wa, Ua, Cws);
  attn_fused<<<256, 1024, 0, stream>>>(EWs, EU, Va, e_out);
  ctx_gemm<<<128, 512, 0, stream>>>(e_out, enc, c_out);
}

// Round 3
// 108.426 us; speedup vs baseline: 1.0815x; 1.0115x over previous
//
#include <hip/hip_runtime.h>

#define B_  8
#define TE_ 256
#define TD_ 128
#define HE_ 512

typedef __attribute__((ext_vector_type(8))) short short8v;
typedef __attribute__((ext_vector_type(4))) float f32x4;
typedef __attribute__((ext_vector_type(2))) float f32x2;

#define C2 2.8853900817779268f   // 2*log2(e)

// wave64 sum via DPP (VALU, no LDS): result valid in lane 63 only.
__device__ __forceinline__ float wave_red_add(float s) {
#define DPPADD(CTRL) \
  s += __int_as_float(__builtin_amdgcn_update_dpp(0, __float_as_int(s), CTRL, 0xf, 0xf, true))
  DPPADD(0x111);  // row_shr:1
  DPPADD(0x112);  // row_shr:2
  DPPADD(0x114);  // row_shr:4
  DPPADD(0x118);  // row_shr:8  -> lane15 of each row holds row sum
  DPPADD(0x142);  // row_bcast:15
  DPPADD(0x143);  // row_bcast:31 -> lane 63 = total
#undef DPPADD
  return s;
}

// 16-lane row sum only (4 DPP steps): lanes 15/31/47/63 hold their row's sum.
__device__ __forceinline__ float row_red_add(float s) {
#define DPPADD(CTRL) \
  s += __int_as_float(__builtin_amdgcn_update_dpp(0, __float_as_int(s), CTRL, 0xf, 0xf, true))
  DPPADD(0x111);
  DPPADD(0x112);
  DPPADD(0x114);
  DPPADD(0x118);
#undef DPPADD
  return s;
}

// packed 2xf32 fma: d = a*b + c per 32-bit half (VOP3P, full rate)
__device__ __forceinline__ f32x2 pk_fma(f32x2 a, f32x2 b, f32x2 c) {
  f32x2 d;
  asm("v_pk_fma_f32 %0, %1, %2, %3" : "=v"(d) : "v"(a), "v"(b), "v"(c));
  return d;
}

// ---- gemm_fused: Cws[3072,512] = [enc;dec] @ (Wa|Ua), trunc-split 3-term bf16 ----
// Epilogue stores exp2(C2*x) for ALL rows:
//   enc rows (0..2047)   -> EW = e^{2*Ws}
//   dec rows (2048..3071)-> EU = e^{2*Uh}
__global__ __launch_bounds__(512) void gemm_fused(
    const float* __restrict__ enc, const float* __restrict__ dec,
    const float* __restrict__ Wa, const float* __restrict__ Ua,
    float* __restrict__ C) {
  __shared__ short BT[2][32][512];    // 64 KB
  const int bid = blockIdx.x;
  const int mt = bid % 24, nt = bid / 24;
  const int m0 = mt * 128, n0 = nt * 32;
  const bool isenc = (mt < 16);
  const float* Bsrc = isenc ? Wa : Ua;
  const float* Asrc = isenc ? enc + (size_t)m0 * 512
                            : dec + (size_t)(m0 - 2048) * 512;
  const int tid = threadIdx.x;
  {
    const int kp = tid >> 3;          // 0..63
    const int c4 = (tid & 7) * 4;
    for (int p = 0; p < 4; ++p) {
      const int k = 2 * kp + p * 128;              // even
      float4 v0 = *(const float4*)(Bsrc + (size_t)k * 512 + n0 + c4);
      float4 v1 = *(const float4*)(Bsrc + (size_t)(k + 1) * 512 + n0 + c4);
      const float a0[4] = {v0.x, v0.y, v0.z, v0.w};
      const float a1[4] = {v1.x, v1.y, v1.z, v1.w};
      const int kc = k >> 3, klo = k & 7;
#pragma unroll
      for (int q = 0; q < 4; ++q) {
        const int n = c4 + q;
        unsigned u0 = __float_as_uint(a0[q]);
        unsigned u1 = __float_as_uint(a1[q]);
        unsigned hi32 = __builtin_amdgcn_perm(u1, u0, 0x07060302);
        float l0 = a0[q] - __uint_as_float(u0 & 0xffff0000u);
        float l1 = a1[q] - __uint_as_float(u1 & 0xffff0000u);
        unsigned lo32 = __builtin_amdgcn_perm(__float_as_uint(l1), __float_as_uint(l0), 0x07060302);
        const int slot = (kc & ~7) | ((kc ^ n) & 7);
        *(unsigned*)&BT[0][n][slot * 8 + klo] = hi32;
        *(unsigned*)&BT[1][n][slot * 8 + klo] = lo32;
      }
    }
  }
  __syncthreads();
  const int w = tid >> 6, lane = tid & 63;
  const int fm = lane & 15, fc = lane >> 4;
  const float* Ap = Asrc + (size_t)(w * 16 + fm) * 512 + fc * 8;
  f32x4 acc0 = {}, acc1 = {};
  float4 pfa[2], pfb[2];
  pfa[0] = *(const float4*)(Ap);
  pfb[0] = *(const float4*)(Ap + 4);
  pfa[1] = *(const float4*)(Ap + 32);
  pfb[1] = *(const float4*)(Ap + 36);
  for (int it = 0; it < 16; ++it) {
    const float4 fa = pfa[it & 1];
    const float4 fb = pfb[it & 1];
    if (it < 14) {
      pfa[it & 1] = *(const float4*)(Ap + (it + 2) * 32);
      pfb[it & 1] = *(const float4*)(Ap + (it + 2) * 32 + 4);
    }
    const float af[8] = {fa.x, fa.y, fa.z, fa.w, fb.x, fb.y, fb.z, fb.w};
    union { unsigned u[4]; short8v s; } ahu, alu;
#pragma unroll
    for (int e = 0; e < 4; ++e) {
      unsigned u0 = __float_as_uint(af[2 * e]);
      unsigned u1 = __float_as_uint(af[2 * e + 1]);
      ahu.u[e] = __builtin_amdgcn_perm(u1, u0, 0x07060302);
      float l0 = af[2 * e]     - __uint_as_float(u0 & 0xffff0000u);
      float l1 = af[2 * e + 1] - __uint_as_float(u1 & 0xffff0000u);
      alu.u[e] = __builtin_amdgcn_perm(__float_as_uint(l1), __float_as_uint(l0), 0x07060302);
    }
    const short8v ah = ahu.s, al = alu.s;
    const int kc = it * 4 + fc;
    const int base = kc & ~7;
    const int s0 = (base | ((kc ^ fm) & 7)) * 8;
    const int s1 = (base | ((kc ^ (16 + fm)) & 7)) * 8;
    short8v bh0 = *(const short8v*)&BT[0][fm][s0];
    short8v bl0 = *(const short8v*)&BT[1][fm][s0];
    short8v bh1 = *(const short8v*)&BT[0][16 + fm][s1];
    short8v bl1 = *(const short8v*)&BT[1][16 + fm][s1];
    acc0 = __builtin_amdgcn_mfma_f32_16x16x32_bf16(ah, bh0, acc0, 0, 0, 0);
    acc1 = __builtin_amdgcn_mfma_f32_16x16x32_bf16(ah, bh1, acc1, 0, 0, 0);
    acc0 = __builtin_amdgcn_mfma_f32_16x16x32_bf16(ah, bl0, acc0, 0, 0, 0);
    acc1 = __builtin_amdgcn_mfma_f32_16x16x32_bf16(ah, bl1, acc1, 0, 0, 0);
    acc0 = __builtin_amdgcn_mfma_f32_16x16x32_bf16(al, bh0, acc0, 0, 0, 0);
    acc1 = __builtin_amdgcn_mfma_f32_16x16x32_bf16(al, bh1, acc1, 0, 0, 0);
  }
  const int row = m0 + w * 16 + fc * 4;
  float* Cp = C + (size_t)row * 512 + n0 + fm;
#pragma unroll
  for (int r = 0; r < 4; ++r)
    Cp[(size_t)r * 512] = __builtin_amdgcn_exp2f(C2 * acc0[r]);
#pragma unroll
  for (int r = 0; r < 4; ++r)
    Cp[(size_t)r * 512 + 16] = __builtin_amdgcn_exp2f(C2 * acc1[r]);
}

// ---- attn_fused: logits + softmax. R16: reciprocal PAIRING on the trans pipe:
//   -va/A - vb/B = (-va*B - vb*A) * rcp(A*B)   -> 1 rcp per 2 h-elems.
// (A,B >= 1, A*B <= ~1e14: safe fp32 range; extra rounding ~2 ulp on |term|<=0.4.)
// EWs holds e^{2Ws}; EU holds e^{2Uh}. tanh term = v - 2v*rcp(EW*EU + 1).
__global__ __launch_bounds__(1024) void attn_fused(
    const float* __restrict__ EWs, const float* __restrict__ EU,
    const float* __restrict__ Va, float* __restrict__ e_out) {
  __shared__ float sEU[4][HE_];      // 8 KB
  __shared__ float sV[HE_];          // 2 KB
  __shared__ float sE4[4][TE_][4];   // 16 KB: 4 row-partials per (d,t)
  __shared__ float sRed[16];
  __shared__ float sNorm[4];
  const int tid = threadIdx.x;
  const int b  = blockIdx.x & 7;          // XCD-aligned b partition
  const int d0 = (blockIdx.x >> 3) * 4;   // 32 d-tiles x 8 b = 256 blocks
  if (tid < 512)
    ((float4*)sEU)[tid] = ((const float4*)(EU + (size_t)(b * TD_ + d0) * HE_))[tid];
  else if (tid < 640)
    ((float4*)sV)[tid - 512] = ((const float4*)Va)[tid - 512];
  __syncthreads();
  const int lane = tid & 63, w = tid >> 6;   // 16 waves
  const int tb = w * 16;                     // 16 t per wave, 4 d's each
  const int h0 = lane * 8;
  f32x2 peU[4][4];
  float nvv[8], sumv = 0.f;
#pragma unroll
  for (int j = 0; j < 8; ++j) {
    const float vj = sV[h0 + j];
    sumv += vj;
    nvv[j] = -2.0f * vj;
  }
#pragma unroll
  for (int d = 0; d < 4; ++d)
#pragma unroll
    for (int jj = 0; jj < 4; ++jj)
      peU[d][jj] = ((const f32x2*)&sEU[d][h0])[jj];
  const f32x2 one2 = {1.0f, 1.0f};
  const float* pw = EWs + ((size_t)b * TE_ + tb) * HE_ + h0;
  f32x2 pX[4];
#pragma unroll
  for (int jj = 0; jj < 4; ++jj) pX[jj] = ((const f32x2*)pw)[jj];
  for (int ti = 0; ti < 16; ++ti) {
    const float* pn = pw + HE_;
    f32x2 nX[4];                           // depth-1 prefetch
#pragma unroll
    for (int jj = 0; jj < 4; ++jj) nX[jj] = ((const f32x2*)pn)[jj];
    float s0 = sumv, s1 = sumv, s2 = sumv, s3 = sumv;
#pragma unroll
    for (int jj = 0; jj < 4; ++jj) {
      const float nva = nvv[2 * jj], nvb = nvv[2 * jj + 1];
#define TPAIR(D, SD) { \
      f32x2 ee = pk_fma(pX[jj], peU[D][jj], one2); \
      float num = nva * ee.y; \
      num = fmaf(nvb, ee.x, num); \
      SD = fmaf(num, __builtin_amdgcn_rcpf(ee.x * ee.y), SD); }
      TPAIR(0, s0)
      TPAIR(1, s1)
      TPAIR(2, s2)
      TPAIR(3, s3)
#undef TPAIR
    }
    s0 = row_red_add(s0);
    s1 = row_red_add(s1);
    s2 = row_red_add(s2);
    s3 = row_red_add(s3);
    if ((lane & 15) == 15) {
      const int r = lane >> 4;
      sE4[0][tb + ti][r] = s0;
      sE4[1][tb + ti][r] = s1;
      sE4[2][tb + ti][r] = s2;
      sE4[3][tb + ti][r] = s3;
    }
    pX[0] = nX[0]; pX[1] = nX[1]; pX[2] = nX[2]; pX[3] = nX[3];
    pw = pn;
  }
  __syncthreads();
  // softmax: 1024 threads = 4 d x 256 t, no divergent branch.
  // (no max-subtraction: |logit| <= sum|V| ~ 21, exp safe in fp32)
  const int dA = tid >> 8, t = tid & 255;
  const float* q = sE4[dA][t];
  const float ex = __expf(q[0] + q[1] + q[2] + q[3]);
  float sum = wave_red_add(ex);
  if (lane == 63) sRed[w] = sum;             // waves 4d..4d+3 belong to d
  __syncthreads();
  if (tid < 4)
    sNorm[tid] = 1.0f / (sRed[tid * 4] + sRed[tid * 4 + 1] + sRed[tid * 4 + 2] + sRed[tid * 4 + 3]);
  __syncthreads();
  e_out[(size_t)(b * TD_ + d0 + dA) * TE_ + t] = ex * sNorm[dA];
}

// ---- ctx_gemm: c[b] = e[b] @ enc[b]  ([128,256]x[256,512] per b), 3-term bf16 ----
// 128 blocks x 512 thr; b = bid&7 keeps each b's enc/e slice on its XCD's L2.
__global__ __launch_bounds__(512) void ctx_gemm(
    const float* __restrict__ e, const float* __restrict__ enc,
    float* __restrict__ c_out) {
  __shared__ short BT[2][32][256];   // 32 KB
  const int bid = blockIdx.x;
  const int b = bid & 7, nt = bid >> 3;    // 16 n-tiles of 32
  const int n0 = nt * 32;
  const float* A    = e   + (size_t)b * TD_ * TE_;   // [128,256]
  const float* Bsrc = enc + (size_t)b * TE_ * HE_;   // [256,512]
  const int tid = threadIdx.x;
  {
    const int kp = tid >> 3;          // 0..63
    const int c4 = (tid & 7) * 4;
    for (int p = 0; p < 2; ++p) {
      const int k = 2 * kp + p * 128;              // even, covers 0..254
      float4 v0 = *(const float4*)(Bsrc + (size_t)k * HE_ + n0 + c4);
      float4 v1 = *(const float4*)(Bsrc + (size_t)(k + 1) * HE_ + n0 + c4);
      const float a0[4] = {v0.x, v0.y, v0.z, v0.w};
      const float a1[4] = {v1.x, v1.y, v1.z, v1.w};
      const int kc = k >> 3, klo = k & 7;
#pragma unroll
      for (int q = 0; q < 4; ++q) {
        const int n = c4 + q;
        unsigned u0 = __float_as_uint(a0[q]);
        unsigned u1 = __float_as_uint(a1[q]);
        unsigned hi32 = __builtin_amdgcn_perm(u1, u0, 0x07060302);
        float l0 = a0[q] - __uint_as_float(u0 & 0xffff0000u);
        float l1 = a1[q] - __uint_as_float(u1 & 0xffff0000u);
        unsigned lo32 = __builtin_amdgcn_perm(__float_as_uint(l1), __float_as_uint(l0), 0x07060302);
        const int slot = (kc & ~7) | ((kc ^ n) & 7);
        *(unsigned*)&BT[0][n][slot * 8 + klo] = hi32;
        *(unsigned*)&BT[1][n][slot * 8 + klo] = lo32;
      }
    }
  }
  __syncthreads();
  const int w = tid >> 6, lane = tid & 63;
  const int fm = lane & 15, fc = lane >> 4;
  const float* Ap = A + (size_t)(w * 16 + fm) * TE_ + fc * 8;
  f32x4 acc0 = {}, acc1 = {};
  for (int it = 0; it < 8; ++it) {
    const float4 fa = *(const float4*)(Ap + it * 32);
    const float4 fb = *(const float4*)(Ap + it * 32 + 4);
    const float af[8] = {fa.x, fa.y, fa.z, fa.w, fb.x, fb.y, fb.z, fb.w};
    union { unsigned u[4]; short8v s; } ahu, alu;
#pragma unroll
    for (int q = 0; q < 4; ++q) {
      unsigned u0 = __float_as_uint(af[2 * q]);
      unsigned u1 = __float_as_uint(af[2 * q + 1]);
      ahu.u[q] = __builtin_amdgcn_perm(u1, u0, 0x07060302);
      float l0 = af[2 * q]     - __uint_as_float(u0 & 0xffff0000u);
      float l1 = af[2 * q + 1] - __uint_as_float(u1 & 0xffff0000u);
      alu.u[q] = __builtin_amdgcn_perm(__float_as_uint(l1), __float_as_uint(l0), 0x07060302);
    }
    const short8v ah = ahu.s, al = alu.s;
    const int kc = it * 4 + fc;
    const int base = kc & ~7;
    const int s0 = (base | ((kc ^ fm) & 7)) * 8;
    const int s1 = (base | ((kc ^ (16 + fm)) & 7)) * 8;
    short8v bh0 = *(const short8v*)&BT[0][fm][s0];
    short8v bl0 = *(const short8v*)&BT[1][fm][s0];
    short8v bh1 = *(const short8v*)&BT[0][16 + fm][s1];
    short8v bl1 = *(const short8v*)&BT[1][16 + fm][s1];
    acc0 = __builtin_amdgcn_mfma_f32_16x16x32_bf16(ah, bh0, acc0, 0, 0, 0);
    acc1 = __builtin_amdgcn_mfma_f32_16x16x32_bf16(ah, bh1, acc1, 0, 0, 0);
    acc0 = __builtin_amdgcn_mfma_f32_16x16x32_bf16(ah, bl0, acc0, 0, 0, 0);
    acc1 = __builtin_amdgcn_mfma_f32_16x16x32_bf16(ah, bl1, acc1, 0, 0, 0);
    acc0 = __builtin_amdgcn_mfma_f32_16x16x32_bf16(al, bh0, acc0, 0, 0, 0);
    acc1 = __builtin_amdgcn_mfma_f32_16x16x32_bf16(al, bh1, acc1, 0, 0, 0);
  }
  const int row = w * 16 + fc * 4;
  float* Cp = c_out + (size_t)(b * TD_ + row) * HE_ + n0 + fm;
#pragma unroll
  for (int r = 0; r < 4; ++r) Cp[(size_t)r * HE_] = acc0[r];
#pragma unroll
  for (int r = 0; r < 4; ++r) Cp[(size_t)r * HE_ + 16] = acc1[r];
}

extern "C" void kernel_launch(void* const* d_in, const int* in_sizes, int n_in,
                              void* d_out, int out_size, void* d_ws, size_t ws_size,
                              hipStream_t stream) {
  const float* enc = (const float*)d_in[0];   // [8,256,512]
  const float* dec = (const float*)d_in[1];   // [8,128,512]
  const float* Wa  = (const float*)d_in[2];   // [512,512]
  const float* Ua  = (const float*)d_in[3];   // [512,512]
  const float* Va  = (const float*)d_in[4];   // [512,1]
  float* c_out = (float*)d_out;
  float* e_out = c_out + (size_t)B_ * TD_ * HE_;
  float* Cws = (float*)d_ws;                   // [3072,512] fp32 = 6 MB
  const float* EWs = Cws;                      // rows 0..2047: e^{2Ws}
  const float* EU  = Cws + (size_t)2048 * 512; // rows 2048..3071: e^{2Uh}
  gemm_fused<<<384, 512, 0, stream>>>(enc, dec, Wa, Ua, Cws);
  attn_fused<<<256, 1024, 0, stream>>>(EWs, EU, Va, e_out);
  ctx_gemm<<<128, 512, 0, stream>>>(e_out, enc, c_out);
}

// Round 5
// 106.965 us; speedup vs baseline: 1.0963x; 1.0137x over previous
//
#include <hip/hip_runtime.h>

#define B_  8
#define TE_ 256
#define TD_ 128
#define HE_ 512

typedef __attribute__((ext_vector_type(8))) short short8v;
typedef __attribute__((ext_vector_type(4))) float f32x4;
typedef __attribute__((ext_vector_type(2))) float f32x2;

#define C2 2.8853900817779268f   // 2*log2(e)

// wave64 sum via DPP (VALU, no LDS): result valid in lane 63 only.
__device__ __forceinline__ float wave_red_add(float s) {
#define DPPADD(CTRL) \
  s += __int_as_float(__builtin_amdgcn_update_dpp(0, __float_as_int(s), CTRL, 0xf, 0xf, true))
  DPPADD(0x111);  // row_shr:1
  DPPADD(0x112);  // row_shr:2
  DPPADD(0x114);  // row_shr:4
  DPPADD(0x118);  // row_shr:8  -> lane15 of each row holds row sum
  DPPADD(0x142);  // row_bcast:15
  DPPADD(0x143);  // row_bcast:31 -> lane 63 = total
#undef DPPADD
  return s;
}

// 16-lane row sum only (4 DPP steps): lanes 15/31/47/63 hold their row's sum.
__device__ __forceinline__ float row_red_add(float s) {
#define DPPADD(CTRL) \
  s += __int_as_float(__builtin_amdgcn_update_dpp(0, __float_as_int(s), CTRL, 0xf, 0xf, true))
  DPPADD(0x111);
  DPPADD(0x112);
  DPPADD(0x114);
  DPPADD(0x118);
#undef DPPADD
  return s;
}

// packed 2xf32 fma: d = a*b + c per 32-bit half (VOP3P, full rate)
__device__ __forceinline__ f32x2 pk_fma(f32x2 a, f32x2 b, f32x2 c) {
  f32x2 d;
  asm("v_pk_fma_f32 %0, %1, %2, %3" : "=v"(d) : "v"(a), "v"(b), "v"(c));
  return d;
}

// ---- gemm_fused: Cws[3072,512] = [enc;dec] @ (Wa|Ua), trunc-split 3-term bf16 ----
// Epilogue stores exp2(C2*x) for ALL rows:
//   enc rows (0..2047)   -> EW = e^{2*Ws}
//   dec rows (2048..3071)-> EU = e^{2*Uh}
__global__ __launch_bounds__(512) void gemm_fused(
    const float* __restrict__ enc, const float* __restrict__ dec,
    const float* __restrict__ Wa, const float* __restrict__ Ua,
    float* __restrict__ C) {
  __shared__ short BT[2][32][512];    // 64 KB
  const int bid = blockIdx.x;
  const int mt = bid % 24, nt = bid / 24;
  const int m0 = mt * 128, n0 = nt * 32;
  const bool isenc = (mt < 16);
  const float* Bsrc = isenc ? Wa : Ua;
  const float* Asrc = isenc ? enc + (size_t)m0 * 512
                            : dec + (size_t)(m0 - 2048) * 512;
  const int tid = threadIdx.x;
  {
    const int kp = tid >> 3;          // 0..63
    const int c4 = (tid & 7) * 4;
    for (int p = 0; p < 4; ++p) {
      const int k = 2 * kp + p * 128;              // even
      float4 v0 = *(const float4*)(Bsrc + (size_t)k * 512 + n0 + c4);
      float4 v1 = *(const float4*)(Bsrc + (size_t)(k + 1) * 512 + n0 + c4);
      const float a0[4] = {v0.x, v0.y, v0.z, v0.w};
      const float a1[4] = {v1.x, v1.y, v1.z, v1.w};
      const int kc = k >> 3, klo = k & 7;
#pragma unroll
      for (int q = 0; q < 4; ++q) {
        const int n = c4 + q;
        unsigned u0 = __float_as_uint(a0[q]);
        unsigned u1 = __float_as_uint(a1[q]);
        unsigned hi32 = __builtin_amdgcn_perm(u1, u0, 0x07060302);
        float l0 = a0[q] - __uint_as_float(u0 & 0xffff0000u);
        float l1 = a1[q] - __uint_as_float(u1 & 0xffff0000u);
        unsigned lo32 = __builtin_amdgcn_perm(__float_as_uint(l1), __float_as_uint(l0), 0x07060302);
        const int slot = (kc & ~7) | ((kc ^ n) & 7);
        *(unsigned*)&BT[0][n][slot * 8 + klo] = hi32;
        *(unsigned*)&BT[1][n][slot * 8 + klo] = lo32;
      }
    }
  }
  __syncthreads();
  const int w = tid >> 6, lane = tid & 63;
  const int fm = lane & 15, fc = lane >> 4;
  const float* Ap = Asrc + (size_t)(w * 16 + fm) * 512 + fc * 8;
  f32x4 acc0 = {}, acc1 = {};
  float4 pfa[2], pfb[2];
  pfa[0] = *(const float4*)(Ap);
  pfb[0] = *(const float4*)(Ap + 4);
  pfa[1] = *(const float4*)(Ap + 32);
  pfb[1] = *(const float4*)(Ap + 36);
  for (int it = 0; it < 16; ++it) {
    const float4 fa = pfa[it & 1];
    const float4 fb = pfb[it & 1];
    if (it < 14) {
      pfa[it & 1] = *(const float4*)(Ap + (it + 2) * 32);
      pfb[it & 1] = *(const float4*)(Ap + (it + 2) * 32 + 4);
    }
    const float af[8] = {fa.x, fa.y, fa.z, fa.w, fb.x, fb.y, fb.z, fb.w};
    union { unsigned u[4]; short8v s; } ahu, alu;
#pragma unroll
    for (int e = 0; e < 4; ++e) {
      unsigned u0 = __float_as_uint(af[2 * e]);
      unsigned u1 = __float_as_uint(af[2 * e + 1]);
      ahu.u[e] = __builtin_amdgcn_perm(u1, u0, 0x07060302);
      float l0 = af[2 * e]     - __uint_as_float(u0 & 0xffff0000u);
      float l1 = af[2 * e + 1] - __uint_as_float(u1 & 0xffff0000u);
      alu.u[e] = __builtin_amdgcn_perm(__float_as_uint(l1), __float_as_uint(l0), 0x07060302);
    }
    const short8v ah = ahu.s, al = alu.s;
    const int kc = it * 4 + fc;
    const int base = kc & ~7;
    const int s0 = (base | ((kc ^ fm) & 7)) * 8;
    const int s1 = (base | ((kc ^ (16 + fm)) & 7)) * 8;
    short8v bh0 = *(const short8v*)&BT[0][fm][s0];
    short8v bl0 = *(const short8v*)&BT[1][fm][s0];
    short8v bh1 = *(const short8v*)&BT[0][16 + fm][s1];
    short8v bl1 = *(const short8v*)&BT[1][16 + fm][s1];
    acc0 = __builtin_amdgcn_mfma_f32_16x16x32_bf16(ah, bh0, acc0, 0, 0, 0);
    acc1 = __builtin_amdgcn_mfma_f32_16x16x32_bf16(ah, bh1, acc1, 0, 0, 0);
    acc0 = __builtin_amdgcn_mfma_f32_16x16x32_bf16(ah, bl0, acc0, 0, 0, 0);
    acc1 = __builtin_amdgcn_mfma_f32_16x16x32_bf16(ah, bl1, acc1, 0, 0, 0);
    acc0 = __builtin_amdgcn_mfma_f32_16x16x32_bf16(al, bh0, acc0, 0, 0, 0);
    acc1 = __builtin_amdgcn_mfma_f32_16x16x32_bf16(al, bh1, acc1, 0, 0, 0);
  }
  const int row = m0 + w * 16 + fc * 4;
  float* Cp = C + (size_t)row * 512 + n0 + fm;
#pragma unroll
  for (int r = 0; r < 4; ++r)
    Cp[(size_t)r * 512] = __builtin_amdgcn_exp2f(C2 * acc0[r]);
#pragma unroll
  for (int r = 0; r < 4; ++r)
    Cp[(size_t)r * 512 + 16] = __builtin_amdgcn_exp2f(C2 * acc1[r]);
}

// ---- attn_fused: logits + softmax. R18: inner loop reverted to the R3-proven
// reciprocal-pairing TPAIR (no op_sel asm — that was the R4 NaN source).
//   -va/A - vb/B = (-va*B - vb*A) * rcp(A*B)   -> 1 rcp per 2 h-elems.
// Epilogue emits split-bf16 hi/lo planes of e for ctx_gemm (kept from R4).
__global__ __launch_bounds__(1024) void attn_fused(
    const float* __restrict__ EWs, const float* __restrict__ EU,
    const float* __restrict__ Va, float* __restrict__ e_out,
    unsigned short* __restrict__ Eh, unsigned short* __restrict__ El) {
  __shared__ float sEU[4][HE_];      // 8 KB
  __shared__ float sV[HE_];          // 2 KB
  __shared__ float sE4[4][TE_][4];   // 16 KB: 4 row-partials per (d,t)
  __shared__ float sRed[16];
  __shared__ float sNorm[4];
  const int tid = threadIdx.x;
  const int b  = blockIdx.x & 7;          // XCD-aligned b partition
  const int d0 = (blockIdx.x >> 3) * 4;   // 32 d-tiles x 8 b = 256 blocks
  if (tid < 512)
    ((float4*)sEU)[tid] = ((const float4*)(EU + (size_t)(b * TD_ + d0) * HE_))[tid];
  else if (tid < 640)
    ((float4*)sV)[tid - 512] = ((const float4*)Va)[tid - 512];
  __syncthreads();
  const int lane = tid & 63, w = tid >> 6;   // 16 waves
  const int tb = w * 16;                     // 16 t per wave, 4 d's each
  const int h0 = lane * 8;
  f32x2 peU[4][4];
  float nvv[8], sumv = 0.f;
#pragma unroll
  for (int j = 0; j < 8; ++j) {
    const float vj = sV[h0 + j];
    sumv += vj;
    nvv[j] = -2.0f * vj;
  }
#pragma unroll
  for (int d = 0; d < 4; ++d)
#pragma unroll
    for (int jj = 0; jj < 4; ++jj)
      peU[d][jj] = ((const f32x2*)&sEU[d][h0])[jj];
  const f32x2 one2 = {1.0f, 1.0f};
  union F4 { float4 v; f32x2 h[2]; };
  const float* pw = EWs + ((size_t)b * TE_ + tb) * HE_ + h0;
  F4 a0, a1;
  a0.v = *(const float4*)(pw);
  a1.v = *(const float4*)(pw + 4);
  for (int ti = 0; ti < 16; ++ti) {
    const float* pn = pw + HE_;
    F4 nA, nB;                               // depth-1 prefetch
    nA.v = *(const float4*)(pn);
    nB.v = *(const float4*)(pn + 4);
    float s0 = sumv, s1 = sumv, s2 = sumv, s3 = sumv;
#pragma unroll
    for (int jj = 0; jj < 4; ++jj) {
      const f32x2 xx = (jj < 2) ? a0.h[jj] : a1.h[jj - 2];
      const float nva = nvv[2 * jj], nvb = nvv[2 * jj + 1];
#define TPAIR(D, SD) { \
      f32x2 ee = pk_fma(xx, peU[D][jj], one2); \
      float num = nva * ee.y; \
      num = fmaf(nvb, ee.x, num); \
      SD = fmaf(num, __builtin_amdgcn_rcpf(ee.x * ee.y), SD); }
      TPAIR(0, s0)
      TPAIR(1, s1)
      TPAIR(2, s2)
      TPAIR(3, s3)
#undef TPAIR
    }
    s0 = row_red_add(s0);
    s1 = row_red_add(s1);
    s2 = row_red_add(s2);
    s3 = row_red_add(s3);
    if ((lane & 15) == 15) {
      const int r = lane >> 4;
      sE4[0][tb + ti][r] = s0;
      sE4[1][tb + ti][r] = s1;
      sE4[2][tb + ti][r] = s2;
      sE4[3][tb + ti][r] = s3;
    }
    a0 = nA; a1 = nB;
    pw = pn;
  }
  __syncthreads();
  // softmax: 1024 threads = 4 d x 256 t, no divergent branch.
  // (no max-subtraction: |logit| <= sum|V| ~ 21, exp safe in fp32)
  const int dA = tid >> 8, t = tid & 255;
  const float* q = sE4[dA][t];
  const float ex = __expf(q[0] + q[1] + q[2] + q[3]);
  float sum = wave_red_add(ex);
  if (lane == 63) sRed[w] = sum;             // waves 4d..4d+3 belong to d
  __syncthreads();
  if (tid < 4)
    sNorm[tid] = 1.0f / (sRed[tid * 4] + sRed[tid * 4 + 1] + sRed[tid * 4 + 2] + sRed[tid * 4 + 3]);
  __syncthreads();
  const float wgt = ex * sNorm[dA];
  const size_t oi = (size_t)(b * TD_ + d0 + dA) * TE_ + t;
  e_out[oi] = wgt;
  // split-bf16 planes (trunc split, same scheme as the GEMMs)
  const unsigned u = __float_as_uint(wgt);
  const float lo_f = wgt - __uint_as_float(u & 0xffff0000u);
  Eh[oi] = (unsigned short)(u >> 16);
  El[oi] = (unsigned short)(__float_as_uint(lo_f) >> 16);
}

// ---- ctx_gemm: c[b] = e[b] @ enc[b]  ([128,256]x[256,512] per b), 3-term bf16 ----
// 256 blocks x 256 thr (1 block/CU, M split 2x64); A consumed as
// pre-split bf16 planes from attn epilogue -> zero A-conversion VALU.
__global__ __launch_bounds__(256) void ctx_gemm(
    const unsigned short* __restrict__ Eh, const unsigned short* __restrict__ El,
    const float* __restrict__ enc, float* __restrict__ c_out) {
  __shared__ short BT[2][32][256];   // 32 KB
  const int bid = blockIdx.x;
  const int b = bid & 7;                   // XCD-aligned
  const int nt = (bid >> 3) & 15;          // 16 n-tiles of 32
  const int m0 = (bid >> 7) * 64;          // 2 m-halves of 64 rows
  const int n0 = nt * 32;
  const float* Bsrc = enc + (size_t)b * TE_ * HE_;   // [256,512]
  const int tid = threadIdx.x;
  {
    const int kp = tid >> 3;          // 0..31
    const int c4 = (tid & 7) * 4;
    for (int p = 0; p < 4; ++p) {
      const int k = 2 * kp + p * 64;               // even, covers 0..254
      float4 v0 = *(const float4*)(Bsrc + (size_t)k * HE_ + n0 + c4);
      float4 v1 = *(const float4*)(Bsrc + (size_t)(k + 1) * HE_ + n0 + c4);
      const float a0[4] = {v0.x, v0.y, v0.z, v0.w};
      const float a1[4] = {v1.x, v1.y, v1.z, v1.w};
      const int kc = k >> 3, klo = k & 7;
#pragma unroll
      for (int q = 0; q < 4; ++q) {
        const int n = c4 + q;
        unsigned u0 = __float_as_uint(a0[q]);
        unsigned u1 = __float_as_uint(a1[q]);
        unsigned hi32 = __builtin_amdgcn_perm(u1, u0, 0x07060302);
        float l0 = a0[q] - __uint_as_float(u0 & 0xffff0000u);
        float l1 = a1[q] - __uint_as_float(u1 & 0xffff0000u);
        unsigned lo32 = __builtin_amdgcn_perm(__float_as_uint(l1), __float_as_uint(l0), 0x07060302);
        const int slot = (kc & ~7) | ((kc ^ n) & 7);
        *(unsigned*)&BT[0][n][slot * 8 + klo] = hi32;
        *(unsigned*)&BT[1][n][slot * 8 + klo] = lo32;
      }
    }
  }
  __syncthreads();
  const int w = tid >> 6, lane = tid & 63;   // 4 waves
  const int fm = lane & 15, fc = lane >> 4;
  const size_t arow = (size_t)(b * TD_ + m0 + w * 16 + fm) * TE_ + fc * 8;
  const unsigned short* Ah = Eh + arow;
  const unsigned short* Al = El + arow;
  f32x4 acc0 = {}, acc1 = {};
  for (int it = 0; it < 8; ++it) {
    const short8v ah = *(const short8v*)(Ah + it * 32);   // 8 bf16 hi, direct frag
    const short8v al = *(const short8v*)(Al + it * 32);
    const int kc = it * 4 + fc;
    const int base = kc & ~7;
    const int s0 = (base | ((kc ^ fm) & 7)) * 8;
    const int s1 = (base | ((kc ^ (16 + fm)) & 7)) * 8;
    short8v bh0 = *(const short8v*)&BT[0][fm][s0];
    short8v bl0 = *(const short8v*)&BT[1][fm][s0];
    short8v bh1 = *(const short8v*)&BT[0][16 + fm][s1];
    short8v bl1 = *(const short8v*)&BT[1][16 + fm][s1];
    acc0 = __builtin_amdgcn_mfma_f32_16x16x32_bf16(ah, bh0, acc0, 0, 0, 0);
    acc1 = __builtin_amdgcn_mfma_f32_16x16x32_bf16(ah, bh1, acc1, 0, 0, 0);
    acc0 = __builtin_amdgcn_mfma_f32_16x16x32_bf16(ah, bl0, acc0, 0, 0, 0);
    acc1 = __builtin_amdgcn_mfma_f32_16x16x32_bf16(ah, bl1, acc1, 0, 0, 0);
    acc0 = __builtin_amdgcn_mfma_f32_16x16x32_bf16(al, bh0, acc0, 0, 0, 0);
    acc1 = __builtin_amdgcn_mfma_f32_16x16x32_bf16(al, bh1, acc1, 0, 0, 0);
  }
  const int row = m0 + w * 16 + fc * 4;
  float* Cp = c_out + (size_t)(b * TD_ + row) * HE_ + n0 + fm;
#pragma unroll
  for (int r = 0; r < 4; ++r) Cp[(size_t)r * HE_] = acc0[r];
#pragma unroll
  for (int r = 0; r < 4; ++r) Cp[(size_t)r * HE_ + 16] = acc1[r];
}

extern "C" void kernel_launch(void* const* d_in, const int* in_sizes, int n_in,
                              void* d_out, int out_size, void* d_ws, size_t ws_size,
                              hipStream_t stream) {
  const float* enc = (const float*)d_in[0];   // [8,256,512]
  const float* dec = (const float*)d_in[1];   // [8,128,512]
  const float* Wa  = (const float*)d_in[2];   // [512,512]
  const float* Ua  = (const float*)d_in[3];   // [512,512]
  const float* Va  = (const float*)d_in[4];   // [512,1]
  float* c_out = (float*)d_out;
  float* e_out = c_out + (size_t)B_ * TD_ * HE_;
  float* Cws = (float*)d_ws;                   // [3072,512] fp32 = 6 MB
  const float* EWs = Cws;                      // rows 0..2047: e^{2Ws}
  const float* EU  = Cws + (size_t)2048 * 512; // rows 2048..3071: e^{2Uh}
  unsigned short* Eh = (unsigned short*)((char*)d_ws + (size_t)3072 * 512 * 4);
  unsigned short* El = Eh + (size_t)B_ * TD_ * TE_;  // 512 KB each
  gemm_fused<<<384, 512, 0, stream>>>(enc, dec, Wa, Ua, Cws);
  attn_fused<<<256, 1024, 0, stream>>>(EWs, EU, Va, e_out, Eh, El);
  ctx_gemm<<<256, 256, 0, stream>>>(Eh, El, enc, c_out);
}